// Round 2
// baseline (347.425 us; speedup 1.0000x reference)
//
#include <hip/hip_runtime.h>
#include <stdint.h>

typedef unsigned short u16;
typedef __attribute__((ext_vector_type(8))) __bf16 bf16x8;
typedef __attribute__((ext_vector_type(4))) float f32x4;

__device__ __forceinline__ u16 f2bf(float f) {
  union { float f; uint32_t u; } v; v.f = f;
  uint32_t u = v.u;
  uint32_t r = (u + 0x7fffu + ((u >> 16) & 1u)) >> 16;  // RNE
  return (u16)r;
}
__device__ __forceinline__ float bf2f(u16 h) {
  union { uint32_t u; float f; } v; v.u = ((uint32_t)h) << 16;
  return v.f;
}

// async 16B/lane global->LDS. LDS dest = wave-uniform base + lane*16 (m104).
__device__ __forceinline__ void gld16(const void* g, void* l) {
  __builtin_amdgcn_global_load_lds(
      (__attribute__((address_space(1))) void*)(uintptr_t)g,
      (__attribute__((address_space(3))) void*)l,
      16, 0, 0);
}

// ---------------- fused fp32 -> bf16 cast of all 5 inputs ----------------
__global__ __launch_bounds__(256) void cast_all(const float* __restrict__ x,
                                                const float* __restrict__ wq,
                                                const float* __restrict__ wk,
                                                const float* __restrict__ wv,
                                                const float* __restrict__ wo,
                                                u16* __restrict__ xb,
                                                u16* __restrict__ wqkv,
                                                u16* __restrict__ wob) {
  int i = blockIdx.x * 256 + threadIdx.x;
  const float* src; u16* dst; int loc, base;
  if (i < 2097152)      { src = x;  dst = xb;   loc = i;           base = 0; }
  else if (i < 3145728) { src = wq; dst = wqkv; loc = i - 2097152; base = 0; }
  else if (i < 3407872) { src = wk; dst = wqkv; loc = i - 3145728; base = 1048576; }
  else if (i < 3670016) { src = wv; dst = wqkv; loc = i - 3407872; base = 1310720; }
  else                  { src = wo; dst = wob;  loc = i - 3670016; base = 0; }
  float4 f = ((const float4*)src)[loc];
  ushort4 o;
  o.x = f2bf(f.x); o.y = f2bf(f.y); o.z = f2bf(f.z); o.w = f2bf(f.w);
  ((ushort4*)dst)[base + loc] = o;
}

// ---------------- bf16 GEMM, C = A * B^T  (BK=64, m97-style staging) ----------------
__global__ __launch_bounds__(256) void gemm_bt(const u16* __restrict__ A,
                                               const u16* __restrict__ B,
                                               void* __restrict__ C,
                                               int M, int N, int K, int out_f32)
{
  __shared__ u16 As[128 * 64];
  __shared__ u16 Bs[128 * 64];
  const int tid  = threadIdx.x;
  const int wave = tid >> 6, lane = tid & 63;
  const int col  = lane & 15, quad = lane >> 4;
  const int bm = blockIdx.y, bn = blockIdx.x;
  const int wm = (wave >> 1) * 64, wn = (wave & 1) * 64;
  const size_t arow0 = (size_t)bm * 128, brow0 = (size_t)bn * 128;

  const int sr = lane >> 3, pc = lane & 7;

  const f32x4 fz = {0.f, 0.f, 0.f, 0.f};
  f32x4 acc[4][4];
  for (int i = 0; i < 4; ++i)
    for (int j = 0; j < 4; ++j) acc[i][j] = fz;

  for (int k0 = 0; k0 < K; k0 += 64) {
    __syncthreads();
    #pragma unroll
    for (int i = 0; i < 4; ++i) {
      int rA = wave * 32 + i * 8 + sr;
      int lc = pc ^ (rA & 7);
      gld16(A + (arow0 + rA) * K + k0 + lc * 8, As + (wave * 32 + i * 8) * 64);
      gld16(B + (brow0 + rA) * K + k0 + lc * 8, Bs + (wave * 32 + i * 8) * 64);
    }
    __syncthreads();
    #pragma unroll
    for (int kk = 0; kk < 2; ++kk) {
      const int swz = (((kk * 4 + quad) ^ (col & 7)) * 8);
      bf16x8 af[4];
      #pragma unroll
      for (int mt = 0; mt < 4; ++mt)
        af[mt] = *(const bf16x8*)&As[(wm + mt * 16 + col) * 64 + swz];
      #pragma unroll
      for (int nt = 0; nt < 4; ++nt) {
        bf16x8 bf = *(const bf16x8*)&Bs[(wn + nt * 16 + col) * 64 + swz];
        #pragma unroll
        for (int mt = 0; mt < 4; ++mt)
          acc[mt][nt] = __builtin_amdgcn_mfma_f32_16x16x32_bf16(af[mt], bf, acc[mt][nt], 0, 0, 0);
      }
    }
  }

  #pragma unroll
  for (int mt = 0; mt < 4; ++mt)
    #pragma unroll
    for (int nt = 0; nt < 4; ++nt)
      #pragma unroll
      for (int i = 0; i < 4; ++i) {
        size_t grow = arow0 + wm + mt * 16 + quad * 4 + i;
        size_t gcol = brow0 + wn + nt * 16 + col;
        float v = acc[mt][nt][i];
        if (out_f32) ((float*)C)[grow * N + gcol] = v;
        else         ((u16*)C)[grow * N + gcol]   = f2bf(v);
      }
}

// ---------------- RoPE over fused qkv buffer (row stride 3072) ----------------
__global__ __launch_bounds__(256) void rope_kernel(u16* __restrict__ t, int S, float qscale) {
  int idx = blockIdx.x * 256 + threadIdx.x;   // total = B*S*20*64
  int i = idx & 63;
  int r = idx >> 6;
  int hh = r % 20; r /= 20;
  int s = r % S;
  int b = r / S;
  float inv = exp2f(-(float)i * 0.20762050593046f);  // 10000^(-2i/128)
  float ang = (float)s * inv;
  float sn, cs;
  __sincosf(ang, &sn, &cs);
  int colb = (hh < 16) ? hh * 128 : 2048 + (hh - 16) * 128;
  float osc = (hh < 16) ? qscale : 1.0f;
  size_t base = (size_t)(b * S + s) * 3072 + colb + 2 * i;
  float t0 = bf2f(t[base]), t1 = bf2f(t[base + 1]);
  t[base]     = f2bf((t0 * cs - t1 * sn) * osc);
  t[base + 1] = f2bf((t0 * sn + t1 * cs) * osc);
}

// ---------------- V transpose: qkv[:,2560+kvh*128+d] -> Vtg[(b*4+kvh)*128+d][s] ----
__global__ __launch_bounds__(256) void vtrans_kernel(const u16* __restrict__ qkv,
                                                     u16* __restrict__ Vtg, int S) {
  __shared__ u16 T[64 * 65];
  const int s0 = blockIdx.x * 64, d0 = blockIdx.y * 64, bk = blockIdx.z;
  const int b = bk >> 2, kvh = bk & 3;
  const u16* src = qkv + (size_t)b * S * 3072 + 2560 + kvh * 128 + d0;
  #pragma unroll 4
  for (int it = 0; it < 16; ++it) {
    int idx = it * 256 + threadIdx.x;
    int r = idx >> 6, c = idx & 63;
    T[c * 65 + r] = src[(size_t)(s0 + r) * 3072 + c];
  }
  __syncthreads();
  #pragma unroll 4
  for (int it = 0; it < 16; ++it) {
    int idx = it * 256 + threadIdx.x;
    int d = idx >> 6, s = idx & 63;
    Vtg[((size_t)bk * 128 + d0 + d) * S + s0 + s] = T[d * 65 + s];
  }
}

// ---------------- causal flash attention, GQA 4:1, no-max softmax ----------------
// 4 waves x 32 q-rows. S^T via swapped MFMA operands -> P b64 writes.
// K double-buffered in LDS: K(kt+1) issued at top of iter kt into the alternate
// buffer, so the single end-of-iter __syncthreads() vmcnt(0) drain is cheap
// (loads had the whole compute phase to land). ONE barrier per tile.
// V^T is NOT staged: fragments read directly from global (L2/L3-resident,
// 64B-segment coalesced); S^T + softmax hides their latency. T5 setprio on MFMA.
__global__ __launch_bounds__(256, 2) void attn_kernel(const u16* __restrict__ QKV,
                                                      const u16* __restrict__ Vtg,
                                                      u16* __restrict__ Ctx,
                                                      int B, int S)
{
  const int x = blockIdx.x;                 // 512 blocks
  const int t = x >> 5, bh = x & 31;
  const int qt = (x < 256) ? (15 - t) : (t - 8);   // heavy first; pairs (c,c+256) sum 15
  const int h = bh & 15, b = bh >> 4;
  const int tid  = threadIdx.x;
  const int wave = tid >> 6, lane = tid & 63;
  const int col  = lane & 15, quad = lane >> 4;
  const int q0   = qt * 128;
  const int kvh  = h >> 2;
  const int row0w = q0 + wave * 32;

  __shared__ u16 Ks[2][64 * 128];  // [buf][key][d], 16B chunks phys = c ^ (key&15)
  __shared__ u16 Ps[4][32 * 72];   // per-wave P: [qrow][key], stride 72

  // Q B-operand frags (scale log2e/sqrt(128) pre-folded in rope)
  bf16x8 aq[2][4];
  #pragma unroll
  for (int mt = 0; mt < 2; ++mt)
    #pragma unroll
    for (int ks = 0; ks < 4; ++ks)
      aq[mt][ks] = *(const bf16x8*)(QKV + (size_t)(b * S + row0w + mt * 16 + col) * 3072
                                        + h * 128 + ks * 32 + quad * 8);
  // consume aq so the compiler's vmcnt wait for these loads lands pre-loop
  #pragma unroll
  for (int mt = 0; mt < 2; ++mt)
    #pragma unroll
    for (int ks = 0; ks < 4; ++ks)
      asm volatile("" :: "v"(__builtin_bit_cast(f32x4, aq[mt][ks])));

  const u16* KVb = QKV + (size_t)b * S * 3072 + 2048 + kvh * 128;
  const u16* Vtb = Vtg + ((size_t)(b * 4 + kvh) * 128) * S;
  u16* Pw = Ps[wave];

  const f32x4 fz = {0.f, 0.f, 0.f, 0.f};
  f32x4 o[2][8];
  #pragma unroll
  for (int mt = 0; mt < 2; ++mt)
    #pragma unroll
    for (int nc = 0; nc < 8; ++nc) o[mt][nc] = fz;
  float rs[2] = {0.f, 0.f};   // per-lane: qrow = row0w + mt*16 + col

  const int kt_max = 2 * qt + 1;

  // prologue: stage K(0) into Ks[0]
  #pragma unroll
  for (int i = 0; i < 4; ++i) {
    int r = wave * 16 + i * 4 + (lane >> 4);
    int lc = (lane & 15) ^ (r & 15);
    gld16(KVb + (size_t)r * 3072 + lc * 8, Ks[0] + (wave * 16 + i * 4) * 128);
  }
  __syncthreads();

  for (int kt = 0; kt <= kt_max; ++kt) {
    // prefetch K(kt+1) into the alternate buffer (read next iter).
    // Safe: buffer (kt+1)&1 was last read in iter kt-1's S^T, which precedes
    // the barrier ending iter kt-1, which precedes this issue.
    if (kt < kt_max) {
      u16* kdst = Ks[(kt + 1) & 1];
      #pragma unroll
      for (int i = 0; i < 4; ++i) {
        int r = wave * 16 + i * 4 + (lane >> 4);
        int lc = (lane & 15) ^ (r & 15);
        gld16(KVb + (size_t)((kt + 1) * 64 + r) * 3072 + lc * 8,
              kdst + (wave * 16 + i * 4) * 128);
      }
    }

    const bool active = (kt * 64 <= row0w + 31);   // wave-uniform
    if (active) {
      const bool need_mask = (kt * 64 + 63 > row0w);
      const u16* Kc = Ks[kt & 1];

      // direct-global V^T fragments; issued here so S^T+softmax hides latency
      bf16x8 bv[8][2];
      #pragma unroll
      for (int nc = 0; nc < 8; ++nc)
        #pragma unroll
        for (int ks = 0; ks < 2; ++ks)
          bv[nc][ks] = *(const bf16x8*)(Vtb + (size_t)(nc * 16 + col) * S
                                            + kt * 64 + (ks * 4 + quad) * 8);

      // S^T = K Q^T per 16-key group; write P[qrow][key] as b64
      #pragma unroll
      for (int nt = 0; nt < 4; ++nt) {
        bf16x8 kA[4];
        #pragma unroll
        for (int ks = 0; ks < 4; ++ks)
          kA[ks] = *(const bf16x8*)&Kc[(nt * 16 + col) * 128 + (((ks * 4 + quad) ^ col) * 8)];
        #pragma unroll
        for (int mt = 0; mt < 2; ++mt) {
          f32x4 st = fz;
          __builtin_amdgcn_s_setprio(1);
          #pragma unroll
          for (int ks = 0; ks < 4; ++ks)
            st = __builtin_amdgcn_mfma_f32_16x16x32_bf16(kA[ks], aq[mt][ks], st, 0, 0, 0);
          __builtin_amdgcn_s_setprio(0);
          // lane: key = kt*64 + nt*16 + quad*4 + i, qrow = row0w + mt*16 + col
          float pv[4];
          const int kbase = kt * 64 + nt * 16 + quad * 4;
          const int qrow  = row0w + mt * 16 + col;
          #pragma unroll
          for (int i = 0; i < 4; ++i) {
            float s = st[i];
            if (need_mask && (kbase + i > qrow)) s = -__builtin_inff();
            pv[i] = exp2f(s);
          }
          rs[mt] += (pv[0] + pv[1]) + (pv[2] + pv[3]);
          uint32_t d0 = (__float_as_uint(pv[0]) >> 16) | (__float_as_uint(pv[1]) & 0xffff0000u);
          uint32_t d1 = (__float_as_uint(pv[2]) >> 16) | (__float_as_uint(pv[3]) & 0xffff0000u);
          uint2 dd; dd.x = d0; dd.y = d1;
          *(uint2*)&Pw[(mt * 16 + col) * 72 + nt * 16 + quad * 4] = dd;
        }
      }
      __asm__ volatile("" ::: "memory");

      // PV: P A-frags (b128), V^T B-frags from registers
      bf16x8 ap[2][2];
      #pragma unroll
      for (int mt = 0; mt < 2; ++mt)
        #pragma unroll
        for (int ks = 0; ks < 2; ++ks)
          ap[mt][ks] = *(const bf16x8*)&Pw[(mt * 16 + col) * 72 + ks * 32 + quad * 8];
      #pragma unroll
      for (int nc = 0; nc < 8; ++nc) {
        #pragma unroll
        for (int ks = 0; ks < 2; ++ks) {
          __builtin_amdgcn_s_setprio(1);
          #pragma unroll
          for (int mt = 0; mt < 2; ++mt)
            o[mt][nc] = __builtin_amdgcn_mfma_f32_16x16x32_bf16(ap[mt][ks], bv[nc][ks], o[mt][nc], 0, 0, 0);
          __builtin_amdgcn_s_setprio(0);
        }
      }
    }

    // single barrier per tile. Its vmcnt(0) drain also retires K(kt+1), which
    // has had the whole compute phase in flight -> cheap. Guards buffer reuse
    // and cross-wave visibility of the staged K.
    __syncthreads();
  }

  // epilogue: reduce rs over the 4 quad-copies, normalize, store
  #pragma unroll
  for (int mt = 0; mt < 2; ++mt) {
    float v = rs[mt];
    v += __shfl_xor(v, 16);
    v += __shfl_xor(v, 32);
    float lv[4];
    #pragma unroll
    for (int i = 0; i < 4; ++i)
      lv[i] = 1.0f / __shfl(v, quad * 4 + i);
    #pragma unroll
    for (int nc = 0; nc < 8; ++nc)
      #pragma unroll
      for (int i = 0; i < 4; ++i) {
        int qg = row0w + mt * 16 + quad * 4 + i;
        Ctx[(size_t)(b * S + qg) * 2048 + h * 128 + nc * 16 + col] =
            f2bf(o[mt][nc][i] * lv[i]);
      }
  }
}

extern "C" void kernel_launch(void* const* d_in, const int* in_sizes, int n_in,
                              void* d_out, int out_size, void* d_ws, size_t ws_size,
                              hipStream_t stream) {
  const int B = 2, S = 2048, D = 2048;
  const int M = B * S;            // 4096
  const int NQKV = 3072;          // q 0..2047 | k 2048..2559 | v 2560..3071

  const float* x  = (const float*)d_in[0];
  const float* wq = (const float*)d_in[1];
  const float* wk = (const float*)d_in[2];
  const float* wv = (const float*)d_in[3];
  const float* wo = (const float*)d_in[4];

  char* ws = (char*)d_ws;
  u16* xb    = (u16*)ws; ws += (size_t)M * D * 2;
  u16* wqkvb = (u16*)ws; ws += (size_t)NQKV * D * 2;
  u16* wob   = (u16*)ws; ws += (size_t)D * D * 2;
  u16* qkvb  = (u16*)ws; ws += (size_t)M * NQKV * 2;
  u16* vtg   = (u16*)ws; ws += (size_t)B * 4 * 128 * S * 2;
  u16* ctx   = (u16*)ws; ws += (size_t)M * D * 2;

  cast_all<<<18432, 256, 0, stream>>>(x, wq, wk, wv, wo, xb, wqkvb, wob);

  gemm_bt<<<dim3(NQKV / 128, M / 128), 256, 0, stream>>>(xb, wqkvb, qkvb, M, NQKV, D, 0);

  // qscale = log2(e)/sqrt(128), folded so attention uses exp2 directly
  const float qscale = 0.12751744515623627f;
  rope_kernel<<<(M * 20 * 64) / 256, 256, 0, stream>>>(qkvb, S, qscale);

  vtrans_kernel<<<dim3(S / 64, 2, B * 4), 256, 0, stream>>>(qkvb, vtg, S);

  attn_kernel<<<512, 256, 0, stream>>>(qkvb, vtg, ctx, B, S);

  gemm_bt<<<dim3(D / 128, M / 128), 256, 0, stream>>>(ctx, wob, d_out, M, D, D, 1);
}

// Round 3
// 316.990 us; speedup vs baseline: 1.0960x; 1.0960x over previous
//
#include <hip/hip_runtime.h>
#include <stdint.h>

typedef unsigned short u16;
typedef __attribute__((ext_vector_type(8))) __bf16 bf16x8;
typedef __attribute__((ext_vector_type(4))) __bf16 bf16x4;
typedef __attribute__((ext_vector_type(4))) float f32x4;

__device__ __forceinline__ u16 f2bf(float f) {
  union { float f; uint32_t u; } v; v.f = f;
  uint32_t u = v.u;
  uint32_t r = (u + 0x7fffu + ((u >> 16) & 1u)) >> 16;  // RNE
  return (u16)r;
}
__device__ __forceinline__ float bf2f(u16 h) {
  union { uint32_t u; float f; } v; v.u = ((uint32_t)h) << 16;
  return v.f;
}

// async 16B/lane global->LDS. LDS dest = wave-uniform base + lane*16 (m104).
__device__ __forceinline__ void gld16(const void* g, void* l) {
  __builtin_amdgcn_global_load_lds(
      (__attribute__((address_space(1))) void*)(uintptr_t)g,
      (__attribute__((address_space(3))) void*)l,
      16, 0, 0);
}

// ---------------- fused fp32 -> bf16 cast of all 5 inputs ----------------
__global__ __launch_bounds__(256) void cast_all(const float* __restrict__ x,
                                                const float* __restrict__ wq,
                                                const float* __restrict__ wk,
                                                const float* __restrict__ wv,
                                                const float* __restrict__ wo,
                                                u16* __restrict__ xb,
                                                u16* __restrict__ wqkv,
                                                u16* __restrict__ wob) {
  int i = blockIdx.x * 256 + threadIdx.x;
  const float* src; u16* dst; int loc, base;
  if (i < 2097152)      { src = x;  dst = xb;   loc = i;           base = 0; }
  else if (i < 3145728) { src = wq; dst = wqkv; loc = i - 2097152; base = 0; }
  else if (i < 3407872) { src = wk; dst = wqkv; loc = i - 3145728; base = 1048576; }
  else if (i < 3670016) { src = wv; dst = wqkv; loc = i - 3407872; base = 1310720; }
  else                  { src = wo; dst = wob;  loc = i - 3670016; base = 0; }
  float4 f = ((const float4*)src)[loc];
  ushort4 o;
  o.x = f2bf(f.x); o.y = f2bf(f.y); o.z = f2bf(f.z); o.w = f2bf(f.w);
  ((ushort4*)dst)[base + loc] = o;
}

// ---------------- bf16 GEMM, C = A * B^T  (BK=64, m97-style staging) ----------------
__global__ __launch_bounds__(256) void gemm_bt(const u16* __restrict__ A,
                                               const u16* __restrict__ B,
                                               void* __restrict__ C,
                                               int M, int N, int K, int out_f32)
{
  __shared__ u16 As[128 * 64];
  __shared__ u16 Bs[128 * 64];
  const int tid  = threadIdx.x;
  const int wave = tid >> 6, lane = tid & 63;
  const int col  = lane & 15, quad = lane >> 4;
  const int bm = blockIdx.y, bn = blockIdx.x;
  const int wm = (wave >> 1) * 64, wn = (wave & 1) * 64;
  const size_t arow0 = (size_t)bm * 128, brow0 = (size_t)bn * 128;

  const int sr = lane >> 3, pc = lane & 7;

  const f32x4 fz = {0.f, 0.f, 0.f, 0.f};
  f32x4 acc[4][4];
  for (int i = 0; i < 4; ++i)
    for (int j = 0; j < 4; ++j) acc[i][j] = fz;

  for (int k0 = 0; k0 < K; k0 += 64) {
    __syncthreads();
    #pragma unroll
    for (int i = 0; i < 4; ++i) {
      int rA = wave * 32 + i * 8 + sr;
      int lc = pc ^ (rA & 7);
      gld16(A + (arow0 + rA) * K + k0 + lc * 8, As + (wave * 32 + i * 8) * 64);
      gld16(B + (brow0 + rA) * K + k0 + lc * 8, Bs + (wave * 32 + i * 8) * 64);
    }
    __syncthreads();
    #pragma unroll
    for (int kk = 0; kk < 2; ++kk) {
      const int swz = (((kk * 4 + quad) ^ (col & 7)) * 8);
      bf16x8 af[4];
      #pragma unroll
      for (int mt = 0; mt < 4; ++mt)
        af[mt] = *(const bf16x8*)&As[(wm + mt * 16 + col) * 64 + swz];
      #pragma unroll
      for (int nt = 0; nt < 4; ++nt) {
        bf16x8 bf = *(const bf16x8*)&Bs[(wn + nt * 16 + col) * 64 + swz];
        #pragma unroll
        for (int mt = 0; mt < 4; ++mt)
          acc[mt][nt] = __builtin_amdgcn_mfma_f32_16x16x32_bf16(af[mt], bf, acc[mt][nt], 0, 0, 0);
      }
    }
  }

  #pragma unroll
  for (int mt = 0; mt < 4; ++mt)
    #pragma unroll
    for (int nt = 0; nt < 4; ++nt)
      #pragma unroll
      for (int i = 0; i < 4; ++i) {
        size_t grow = arow0 + wm + mt * 16 + quad * 4 + i;
        size_t gcol = brow0 + wn + nt * 16 + col;
        float v = acc[mt][nt][i];
        if (out_f32) ((float*)C)[grow * N + gcol] = v;
        else         ((u16*)C)[grow * N + gcol]   = f2bf(v);
      }
}

// ---------------- RoPE over fused qkv buffer (row stride 3072) ----------------
__global__ __launch_bounds__(256) void rope_kernel(u16* __restrict__ t, int S, float qscale) {
  int idx = blockIdx.x * 256 + threadIdx.x;   // total = B*S*20*64
  int i = idx & 63;
  int r = idx >> 6;
  int hh = r % 20; r /= 20;
  int s = r % S;
  int b = r / S;
  float inv = exp2f(-(float)i * 0.20762050593046f);  // 10000^(-2i/128)
  float ang = (float)s * inv;
  float sn, cs;
  __sincosf(ang, &sn, &cs);
  int colb = (hh < 16) ? hh * 128 : 2048 + (hh - 16) * 128;
  float osc = (hh < 16) ? qscale : 1.0f;
  size_t base = (size_t)(b * S + s) * 3072 + colb + 2 * i;
  float t0 = bf2f(t[base]), t1 = bf2f(t[base + 1]);
  t[base]     = f2bf((t0 * cs - t1 * sn) * osc);
  t[base + 1] = f2bf((t0 * sn + t1 * cs) * osc);
}

// ---------------- V transpose: qkv[:,2560+kvh*128+d] -> Vtg[(b*4+kvh)*128+d][s] ----
__global__ __launch_bounds__(256) void vtrans_kernel(const u16* __restrict__ qkv,
                                                     u16* __restrict__ Vtg, int S) {
  __shared__ u16 T[64 * 65];
  const int s0 = blockIdx.x * 64, d0 = blockIdx.y * 64, bk = blockIdx.z;
  const int b = bk >> 2, kvh = bk & 3;
  const u16* src = qkv + (size_t)b * S * 3072 + 2560 + kvh * 128 + d0;
  #pragma unroll 4
  for (int it = 0; it < 16; ++it) {
    int idx = it * 256 + threadIdx.x;
    int r = idx >> 6, c = idx & 63;
    T[c * 65 + r] = src[(size_t)(s0 + r) * 3072 + c];
  }
  __syncthreads();
  #pragma unroll 4
  for (int it = 0; it < 16; ++it) {
    int idx = it * 256 + threadIdx.x;
    int d = idx >> 6, s = idx & 63;
    Vtg[((size_t)bk * 128 + d0 + d) * S + s0 + s] = T[d * 65 + s];
  }
}

// ---------------- causal flash attention, GQA 4:1, no-max softmax ----------------
// 4 waves x 32 q-rows. S^T via swapped MFMA operands.
// K AND V double-buffered in LDS, issued ONE ITERATION EARLY:
//   for kt: { __syncthreads(); issue K/V(kt+1) -> buf (kt+1)&1; compute(kt) }
// The barrier's vmcnt(0) drain retires loads that had a full compute phase in
// flight -> cheap. ONE barrier/tile, no counted vmcnt, no raw barriers.
// P is per-wave (no cross-wave sharing) and split into two 32-key halves so
// LDS fits 2 blocks/CU: 32K (K dbuf) + 32K (V dbuf) + 8K (P) = 72K.
// P layout: [row][32 keys], 8B granules XOR-swizzled by (row&7) -> <=2-way.
__global__ __launch_bounds__(256, 2) void attn_kernel(const u16* __restrict__ QKV,
                                                      const u16* __restrict__ Vtg,
                                                      u16* __restrict__ Ctx,
                                                      int B, int S)
{
  const int x = blockIdx.x;                 // 512 blocks
  const int t = x >> 5, bh = x & 31;
  const int qt = (x < 256) ? (15 - t) : (t - 8);   // heavy first; pairs (c,c+256) sum 15
  const int h = bh & 15, b = bh >> 4;
  const int tid  = threadIdx.x;
  const int wave = tid >> 6, lane = tid & 63;
  const int col  = lane & 15, quad = lane >> 4;
  const int q0   = qt * 128;
  const int kvh  = h >> 2;
  const int row0w = q0 + wave * 32;

  __shared__ u16 Ks[2][64 * 128];  // [buf][key][d], 16B chunks phys = c ^ (key&15)
  __shared__ u16 Vt[2][128 * 64];  // [buf][d][key], 16B chunks phys = c ^ (d&7)
  __shared__ u16 Ps[4][32 * 32];   // per-wave P half: [qrow][32 keys], swizzled

  // Q B-operand frags (scale log2e/sqrt(128) pre-folded in rope)
  bf16x8 aq[2][4];
  #pragma unroll
  for (int mt = 0; mt < 2; ++mt)
    #pragma unroll
    for (int ks = 0; ks < 4; ++ks)
      aq[mt][ks] = *(const bf16x8*)(QKV + (size_t)(b * S + row0w + mt * 16 + col) * 3072
                                        + h * 128 + ks * 32 + quad * 8);
  // consume aq so the compiler's vmcnt wait for these loads lands pre-loop
  #pragma unroll
  for (int mt = 0; mt < 2; ++mt)
    #pragma unroll
    for (int ks = 0; ks < 4; ++ks)
      asm volatile("" :: "v"(__builtin_bit_cast(f32x4, aq[mt][ks])));

  const u16* KVb = QKV + (size_t)b * S * 3072 + 2048 + kvh * 128;
  const u16* Vtb = Vtg + ((size_t)(b * 4 + kvh) * 128) * S;
  u16* Pw = Ps[wave];

  const f32x4 fz = {0.f, 0.f, 0.f, 0.f};
  f32x4 o[2][8];
  #pragma unroll
  for (int mt = 0; mt < 2; ++mt)
    #pragma unroll
    for (int nc = 0; nc < 8; ++nc) o[mt][nc] = fz;
  float rs[2] = {0.f, 0.f};   // per-lane: qrow = row0w + mt*16 + col

  const int kt_max = 2 * qt + 1;

  // staging lane constants
  const int krow = (lane >> 4);          // K: 4 rows/issue
  const int kcol = (lane & 15);
  const int vrow = (lane >> 3);          // V: 8 rows/issue
  const int vcol = (lane & 7);

  // prologue: issue K(0),V(0) into buf 0
  #pragma unroll
  for (int i = 0; i < 4; ++i) {
    int r = wave * 16 + i * 4 + krow;
    int lc = kcol ^ (r & 15);
    gld16(KVb + (size_t)r * 3072 + lc * 8, Ks[0] + (wave * 16 + i * 4) * 128);
  }
  #pragma unroll
  for (int i = 0; i < 4; ++i) {
    int r = wave * 32 + i * 8 + vrow;
    int lc = vcol ^ (r & 7);
    gld16(Vtb + (size_t)r * S + lc * 8, Vt[0] + (wave * 32 + i * 8) * 64);
  }

  for (int kt = 0; kt <= kt_max; ++kt) {
    // drain (cheap: tile-kt loads flew during compute(kt-1)) + buffer handoff
    __syncthreads();

    // prefetch tile kt+1 into alternate buffers (read next iter).
    // Race-free: buf (kt+1)&1 was last read in compute(kt-1), before this barrier.
    if (kt < kt_max) {
      u16* kdst = Ks[(kt + 1) & 1];
      u16* vdst = Vt[(kt + 1) & 1];
      #pragma unroll
      for (int i = 0; i < 4; ++i) {
        int r = wave * 16 + i * 4 + krow;
        int lc = kcol ^ (r & 15);
        gld16(KVb + (size_t)((kt + 1) * 64 + r) * 3072 + lc * 8,
              kdst + (wave * 16 + i * 4) * 128);
      }
      #pragma unroll
      for (int i = 0; i < 4; ++i) {
        int r = wave * 32 + i * 8 + vrow;
        int lc = vcol ^ (r & 7);
        gld16(Vtb + (size_t)r * S + (kt + 1) * 64 + lc * 8,
              vdst + (wave * 32 + i * 8) * 64);
      }
    }

    if (kt * 64 > row0w + 31) continue;   // wave fully masked (uniform)
    const bool need_mask = (kt * 64 + 63 > row0w);
    const u16* Kc = Ks[kt & 1];
    const u16* Vc = Vt[kt & 1];

    // two 32-key halves: S^T(half) -> softmax -> P write -> PV(half)
    #pragma unroll
    for (int half = 0; half < 2; ++half) {
      #pragma unroll
      for (int ntl = 0; ntl < 2; ++ntl) {
        const int nt = half * 2 + ntl;
        bf16x8 kA[4];
        #pragma unroll
        for (int ks = 0; ks < 4; ++ks)
          kA[ks] = *(const bf16x8*)&Kc[(nt * 16 + col) * 128 + (((ks * 4 + quad) ^ col) * 8)];
        #pragma unroll
        for (int mt = 0; mt < 2; ++mt) {
          f32x4 st = fz;
          __builtin_amdgcn_s_setprio(1);
          #pragma unroll
          for (int ks = 0; ks < 4; ++ks)
            st = __builtin_amdgcn_mfma_f32_16x16x32_bf16(kA[ks], aq[mt][ks], st, 0, 0, 0);
          __builtin_amdgcn_s_setprio(0);
          // lane: key = kt*64 + nt*16 + quad*4 + i, qrow = row0w + mt*16 + col
          float pv[4];
          const int kbase = kt * 64 + nt * 16 + quad * 4;
          const int qrow  = row0w + mt * 16 + col;
          #pragma unroll
          for (int i = 0; i < 4; ++i) {
            float s = st[i];
            if (need_mask && (kbase + i > qrow)) s = -__builtin_inff();
            pv[i] = exp2f(s);
          }
          rs[mt] += (pv[0] + pv[1]) + (pv[2] + pv[3]);
          uint32_t d0 = (__float_as_uint(pv[0]) >> 16) | (__float_as_uint(pv[1]) & 0xffff0000u);
          uint32_t d1 = (__float_as_uint(pv[2]) >> 16) | (__float_as_uint(pv[3]) & 0xffff0000u);
          uint2 dd; dd.x = d0; dd.y = d1;
          // P half layout: row=mt*16+col, granule g = ntl*4+quad, phys g^(row&7)
          const int prow = mt * 16 + col;
          *(uint2*)&Pw[prow * 32 + (((ntl * 4 + quad) ^ (col & 7)) * 4)] = dd;
        }
      }
      __asm__ volatile("" ::: "memory");

      // A-frags for this half: keys quad*8..quad*8+7 -> granules quad*2, quad*2+1
      bf16x8 ap[2];
      #pragma unroll
      for (int mt = 0; mt < 2; ++mt) {
        const int prow = mt * 16 + col;
        bf16x4 lo = *(const bf16x4*)&Pw[prow * 32 + (((quad * 2 + 0) ^ (col & 7)) * 4)];
        bf16x4 hi = *(const bf16x4*)&Pw[prow * 32 + (((quad * 2 + 1) ^ (col & 7)) * 4)];
        ap[mt] = __builtin_shufflevector(lo, hi, 0, 1, 2, 3, 4, 5, 6, 7);
      }
      // PV for this half (ks = half)
      #pragma unroll
      for (int nc = 0; nc < 8; ++nc) {
        bf16x8 bv = *(const bf16x8*)&Vc[(nc * 16 + col) * 64 + (((half * 4 + quad) ^ (col & 7)) * 8)];
        __builtin_amdgcn_s_setprio(1);
        #pragma unroll
        for (int mt = 0; mt < 2; ++mt)
          o[mt][nc] = __builtin_amdgcn_mfma_f32_16x16x32_bf16(ap[mt], bv, o[mt][nc], 0, 0, 0);
        __builtin_amdgcn_s_setprio(0);
      }
    }
  }

  // epilogue: reduce rs over the 4 quad-copies, normalize, store
  #pragma unroll
  for (int mt = 0; mt < 2; ++mt) {
    float v = rs[mt];
    v += __shfl_xor(v, 16);
    v += __shfl_xor(v, 32);
    float lv[4];
    #pragma unroll
    for (int i = 0; i < 4; ++i)
      lv[i] = 1.0f / __shfl(v, quad * 4 + i);
    #pragma unroll
    for (int nc = 0; nc < 8; ++nc)
      #pragma unroll
      for (int i = 0; i < 4; ++i) {
        int qg = row0w + mt * 16 + quad * 4 + i;
        Ctx[(size_t)(b * S + qg) * 2048 + h * 128 + nc * 16 + col] =
            f2bf(o[mt][nc][i] * lv[i]);
      }
  }
}

extern "C" void kernel_launch(void* const* d_in, const int* in_sizes, int n_in,
                              void* d_out, int out_size, void* d_ws, size_t ws_size,
                              hipStream_t stream) {
  const int B = 2, S = 2048, D = 2048;
  const int M = B * S;            // 4096
  const int NQKV = 3072;          // q 0..2047 | k 2048..2559 | v 2560..3071

  const float* x  = (const float*)d_in[0];
  const float* wq = (const float*)d_in[1];
  const float* wk = (const float*)d_in[2];
  const float* wv = (const float*)d_in[3];
  const float* wo = (const float*)d_in[4];

  char* ws = (char*)d_ws;
  u16* xb    = (u16*)ws; ws += (size_t)M * D * 2;
  u16* wqkvb = (u16*)ws; ws += (size_t)NQKV * D * 2;
  u16* wob   = (u16*)ws; ws += (size_t)D * D * 2;
  u16* qkvb  = (u16*)ws; ws += (size_t)M * NQKV * 2;
  u16* vtg   = (u16*)ws; ws += (size_t)B * 4 * 128 * S * 2;
  u16* ctx   = (u16*)ws; ws += (size_t)M * D * 2;

  cast_all<<<18432, 256, 0, stream>>>(x, wq, wk, wv, wo, xb, wqkvb, wob);

  gemm_bt<<<dim3(NQKV / 128, M / 128), 256, 0, stream>>>(xb, wqkvb, qkvb, M, NQKV, D, 0);

  // qscale = log2(e)/sqrt(128), folded so attention uses exp2 directly
  const float qscale = 0.12751744515623627f;
  rope_kernel<<<(M * 20 * 64) / 256, 256, 0, stream>>>(qkvb, S, qscale);

  vtrans_kernel<<<dim3(S / 64, 2, B * 4), 256, 0, stream>>>(qkvb, vtg, S);

  attn_kernel<<<512, 256, 0, stream>>>(qkvb, vtg, ctx, B, S);

  gemm_bt<<<dim3(D / 128, M / 128), 256, 0, stream>>>(ctx, wob, d_out, M, D, D, 1);
}

// Round 4
// 296.948 us; speedup vs baseline: 1.1700x; 1.0675x over previous
//
#include <hip/hip_runtime.h>
#include <stdint.h>

typedef unsigned short u16;
typedef __attribute__((ext_vector_type(8))) __bf16 bf16x8;
typedef __attribute__((ext_vector_type(4))) float f32x4;

__device__ __forceinline__ u16 f2bf(float f) {
  union { float f; uint32_t u; } v; v.f = f;
  uint32_t u = v.u;
  uint32_t r = (u + 0x7fffu + ((u >> 16) & 1u)) >> 16;  // RNE
  return (u16)r;
}
__device__ __forceinline__ float bf2f(u16 h) {
  union { uint32_t u; float f; } v; v.u = ((uint32_t)h) << 16;
  return v.f;
}

// async 16B/lane global->LDS. LDS dest = wave-uniform base + lane*16 (m104).
__device__ __forceinline__ void gld16(const void* g, void* l) {
  __builtin_amdgcn_global_load_lds(
      (__attribute__((address_space(1))) void*)(uintptr_t)g,
      (__attribute__((address_space(3))) void*)l,
      16, 0, 0);
}

// ---------------- fused fp32 -> bf16 cast of all 5 inputs ----------------
__global__ __launch_bounds__(256) void cast_all(const float* __restrict__ x,
                                                const float* __restrict__ wq,
                                                const float* __restrict__ wk,
                                                const float* __restrict__ wv,
                                                const float* __restrict__ wo,
                                                u16* __restrict__ xb,
                                                u16* __restrict__ wqkv,
                                                u16* __restrict__ wob) {
  int i = blockIdx.x * 256 + threadIdx.x;
  const float* src; u16* dst; int loc, base;
  if (i < 2097152)      { src = x;  dst = xb;   loc = i;           base = 0; }
  else if (i < 3145728) { src = wq; dst = wqkv; loc = i - 2097152; base = 0; }
  else if (i < 3407872) { src = wk; dst = wqkv; loc = i - 3145728; base = 1048576; }
  else if (i < 3670016) { src = wv; dst = wqkv; loc = i - 3407872; base = 1310720; }
  else                  { src = wo; dst = wob;  loc = i - 3670016; base = 0; }
  float4 f = ((const float4*)src)[loc];
  ushort4 o;
  o.x = f2bf(f.x); o.y = f2bf(f.y); o.z = f2bf(f.z); o.w = f2bf(f.w);
  ((ushort4*)dst)[base + loc] = o;
}

// ---------------- bf16 GEMM, C = A * B^T  (BK=64, m97-style staging) ----------------
// do_rope: fused RoPE epilogue for the QKV GEMM (cols<2560 rotated; q cols also
// scaled by log2e/sqrt(128)). XCD-contiguous block swizzle (T1) for L2 locality.
__global__ __launch_bounds__(256) void gemm_bt(const u16* __restrict__ A,
                                               const u16* __restrict__ B,
                                               void* __restrict__ C,
                                               int M, int N, int K, int out_f32,
                                               int do_rope)
{
  __shared__ u16 As[128 * 64];
  __shared__ u16 Bs[128 * 64];
  const int tid  = threadIdx.x;
  const int wave = tid >> 6, lane = tid & 63;
  const int col  = lane & 15, quad = lane >> 4;

  // T1: XCD-contiguous work remap. HW round-robins blocks over 8 XCDs by
  // dispatch id, so work item swz = (flat&7)*(nwg/8) + flat/8 gives each XCD a
  // contiguous bm-slab (A-panel L2-resident). Grids here are %8==0 (guarded).
  const int nwg = gridDim.x * gridDim.y;
  int flat = blockIdx.y * gridDim.x + blockIdx.x;
  int swz  = (nwg & 7) ? flat : ((flat & 7) * (nwg >> 3) + (flat >> 3));
  const int bm = swz / gridDim.x, bn = swz % gridDim.x;

  const int wm = (wave >> 1) * 64, wn = (wave & 1) * 64;
  const size_t arow0 = (size_t)bm * 128, brow0 = (size_t)bn * 128;

  const int sr = lane >> 3, pc = lane & 7;

  const f32x4 fz = {0.f, 0.f, 0.f, 0.f};
  f32x4 acc[4][4];
  for (int i = 0; i < 4; ++i)
    for (int j = 0; j < 4; ++j) acc[i][j] = fz;

  for (int k0 = 0; k0 < K; k0 += 64) {
    __syncthreads();
    #pragma unroll
    for (int i = 0; i < 4; ++i) {
      int rA = wave * 32 + i * 8 + sr;
      int lc = pc ^ (rA & 7);
      gld16(A + (arow0 + rA) * K + k0 + lc * 8, As + (wave * 32 + i * 8) * 64);
      gld16(B + (brow0 + rA) * K + k0 + lc * 8, Bs + (wave * 32 + i * 8) * 64);
    }
    __syncthreads();
    #pragma unroll
    for (int kk = 0; kk < 2; ++kk) {
      const int swzk = (((kk * 4 + quad) ^ (col & 7)) * 8);
      bf16x8 af[4];
      #pragma unroll
      for (int mt = 0; mt < 4; ++mt)
        af[mt] = *(const bf16x8*)&As[(wm + mt * 16 + col) * 64 + swzk];
      #pragma unroll
      for (int nt = 0; nt < 4; ++nt) {
        bf16x8 bf = *(const bf16x8*)&Bs[(wn + nt * 16 + col) * 64 + swzk];
        #pragma unroll
        for (int mt = 0; mt < 4; ++mt)
          acc[mt][nt] = __builtin_amdgcn_mfma_f32_16x16x32_bf16(af[mt], bf, acc[mt][nt], 0, 0, 0);
      }
    }
  }

  // epilogue (+ optional fused RoPE: pair partner d^1 lives in lane^1)
  const float qscale = 0.12751744515623627f;  // log2(e)/sqrt(128)
  #pragma unroll
  for (int mt = 0; mt < 4; ++mt)
    #pragma unroll
    for (int nt = 0; nt < 4; ++nt) {
      const size_t gcol = brow0 + wn + nt * 16 + col;
      // wave-uniform: 16-col group entirely inside or outside the rope region
      const bool rope_here = do_rope && (gcol < 2560);
      const int  d    = (int)(gcol & 127);
      const float osc = (gcol < 2048) ? qscale : 1.0f;
      const float inv = exp2f(-(float)(d >> 1) * 0.20762050593046f);  // 10000^(-2i/128)
      const bool odd  = (d & 1) != 0;
      #pragma unroll
      for (int i = 0; i < 4; ++i) {
        size_t grow = arow0 + wm + mt * 16 + quad * 4 + i;
        float v = acc[mt][nt][i];
        if (rope_here) {
          float p = __shfl_xor(v, 1);            // partner column d^1
          float ang = (float)(int)(grow & 2047) * inv;  // s = token pos (S=2048)
          float sn, cs;
          __sincosf(ang, &sn, &cs);
          v = odd ? (p * sn + v * cs) * osc : (v * cs - p * sn) * osc;
        }
        if (out_f32) ((float*)C)[grow * N + gcol] = v;
        else         ((u16*)C)[grow * N + gcol]   = f2bf(v);
      }
    }
}

// ---------------- V transpose: qkv[:,2560+kvh*128+d] -> Vtg[(b*4+kvh)*128+d][s] ----
__global__ __launch_bounds__(256) void vtrans_kernel(const u16* __restrict__ qkv,
                                                     u16* __restrict__ Vtg, int S) {
  __shared__ u16 T[64 * 65];
  const int s0 = blockIdx.x * 64, d0 = blockIdx.y * 64, bk = blockIdx.z;
  const int b = bk >> 2, kvh = bk & 3;
  const u16* src = qkv + (size_t)b * S * 3072 + 2560 + kvh * 128 + d0;
  #pragma unroll 4
  for (int it = 0; it < 16; ++it) {
    int idx = it * 256 + threadIdx.x;
    int r = idx >> 6, c = idx & 63;
    T[c * 65 + r] = src[(size_t)(s0 + r) * 3072 + c];
  }
  __syncthreads();
  #pragma unroll 4
  for (int it = 0; it < 16; ++it) {
    int idx = it * 256 + threadIdx.x;
    int d = idx >> 6, s = idx & 63;
    Vtg[((size_t)bk * 128 + d0 + d) * S + s0 + s] = T[d * 65 + s];
  }
}

// ---------------- causal flash attention, GQA 4:1, no-max softmax ----------------
// (round-0 structure, verbatim: 2 barriers/tile, single-buffered K/V staging)
__global__ __launch_bounds__(256, 2) void attn_kernel(const u16* __restrict__ QKV,
                                                      const u16* __restrict__ Vtg,
                                                      u16* __restrict__ Ctx,
                                                      int B, int S)
{
  const int x = blockIdx.x;                 // 512 blocks
  const int t = x >> 5, bh = x & 31;
  const int qt = (x < 256) ? (15 - t) : (t - 8);   // heavy first; pairs (c,c+256) sum 15
  const int h = bh & 15, b = bh >> 4;
  const int tid  = threadIdx.x;
  const int wave = tid >> 6, lane = tid & 63;
  const int col  = lane & 15, quad = lane >> 4;
  const int q0   = qt * 128;
  const int kvh  = h >> 2;
  const int row0w = q0 + wave * 32;

  __shared__ u16 Ks[64 * 128];    // [key][d], 16B chunks phys = c ^ (key&15)
  __shared__ u16 Vt[128 * 64];    // [d][key], 16B chunks phys = c ^ (d&7)
  __shared__ u16 Ps[4][32 * 72];  // per-wave P: [qrow][key], stride 72

  // Q B-operand frags (scale log2e/sqrt(128) pre-folded in rope)
  bf16x8 aq[2][4];
  #pragma unroll
  for (int mt = 0; mt < 2; ++mt)
    #pragma unroll
    for (int ks = 0; ks < 4; ++ks)
      aq[mt][ks] = *(const bf16x8*)(QKV + (size_t)(b * S + row0w + mt * 16 + col) * 3072
                                        + h * 128 + ks * 32 + quad * 8);

  const u16* KVb = QKV + (size_t)b * S * 3072 + 2048 + kvh * 128;
  const u16* Vtb = Vtg + ((size_t)(b * 4 + kvh) * 128) * S;
  u16* Pw = Ps[wave];

  const f32x4 fz = {0.f, 0.f, 0.f, 0.f};
  f32x4 o[2][8];
  #pragma unroll
  for (int mt = 0; mt < 2; ++mt)
    #pragma unroll
    for (int nc = 0; nc < 8; ++nc) o[mt][nc] = fz;
  float rs[2] = {0.f, 0.f};   // per-lane: qrow = row0w + mt*16 + col

  const int kt_max = 2 * qt + 1;

  for (int kt = 0; kt <= kt_max; ++kt) {
    __syncthreads();   // prior tile reads done
    // stage K: 64 rows x 16 chunks; per wave 4 issues x 4 rows
    #pragma unroll
    for (int i = 0; i < 4; ++i) {
      int r = wave * 16 + i * 4 + (lane >> 4);
      int lc = (lane & 15) ^ (r & 15);
      gld16(KVb + (size_t)(kt * 64 + r) * 3072 + lc * 8, Ks + (wave * 16 + i * 4) * 128);
    }
    // stage V^T: 128 rows x 8 chunks; per wave 4 issues x 8 rows
    #pragma unroll
    for (int i = 0; i < 4; ++i) {
      int r = wave * 32 + i * 8 + (lane >> 3);
      int lc = (lane & 7) ^ (r & 7);
      gld16(Vtb + (size_t)r * S + kt * 64 + lc * 8, Vt + (wave * 32 + i * 8) * 64);
    }
    __syncthreads();   // drain -> staged data visible

    if (kt * 64 > row0w + 31) continue;   // wave fully masked (uniform; barriers above)
    const bool need_mask = (kt * 64 + 63 > row0w);

    // S^T = K Q^T per 16-key group; write P[qrow][key] as b64
    #pragma unroll
    for (int nt = 0; nt < 4; ++nt) {
      bf16x8 kA[4];
      #pragma unroll
      for (int ks = 0; ks < 4; ++ks)
        kA[ks] = *(const bf16x8*)&Ks[(nt * 16 + col) * 128 + (((ks * 4 + quad) ^ col) * 8)];
      #pragma unroll
      for (int mt = 0; mt < 2; ++mt) {
        f32x4 st = fz;
        #pragma unroll
        for (int ks = 0; ks < 4; ++ks)
          st = __builtin_amdgcn_mfma_f32_16x16x32_bf16(kA[ks], aq[mt][ks], st, 0, 0, 0);
        // lane: key = kt*64 + nt*16 + quad*4 + i, qrow = row0w + mt*16 + col
        float pv[4];
        const int kbase = kt * 64 + nt * 16 + quad * 4;
        const int qrow  = row0w + mt * 16 + col;
        #pragma unroll
        for (int i = 0; i < 4; ++i) {
          float s = st[i];
          if (need_mask && (kbase + i > qrow)) s = -__builtin_inff();
          pv[i] = exp2f(s);
        }
        rs[mt] += (pv[0] + pv[1]) + (pv[2] + pv[3]);
        uint32_t d0 = (__float_as_uint(pv[0]) >> 16) | (__float_as_uint(pv[1]) & 0xffff0000u);
        uint32_t d1 = (__float_as_uint(pv[2]) >> 16) | (__float_as_uint(pv[3]) & 0xffff0000u);
        uint2 dd; dd.x = d0; dd.y = d1;
        *(uint2*)&Pw[(mt * 16 + col) * 72 + nt * 16 + quad * 4] = dd;
      }
    }
    __asm__ volatile("" ::: "memory");

    // PV: P A-frags (b128), V^T B-frags read once, reused across mt
    bf16x8 ap[2][2];
    #pragma unroll
    for (int mt = 0; mt < 2; ++mt)
      #pragma unroll
      for (int ks = 0; ks < 2; ++ks)
        ap[mt][ks] = *(const bf16x8*)&Pw[(mt * 16 + col) * 72 + ks * 32 + quad * 8];
    #pragma unroll
    for (int nc = 0; nc < 8; ++nc) {
      #pragma unroll
      for (int ks = 0; ks < 2; ++ks) {
        bf16x8 bv = *(const bf16x8*)&Vt[(nc * 16 + col) * 64 + (((ks * 4 + quad) ^ (col & 7)) * 8)];
        #pragma unroll
        for (int mt = 0; mt < 2; ++mt)
          o[mt][nc] = __builtin_amdgcn_mfma_f32_16x16x32_bf16(ap[mt][ks], bv, o[mt][nc], 0, 0, 0);
      }
    }
  }

  // epilogue: reduce rs over the 4 quad-copies, normalize, store
  #pragma unroll
  for (int mt = 0; mt < 2; ++mt) {
    float v = rs[mt];
    v += __shfl_xor(v, 16);
    v += __shfl_xor(v, 32);
    float lv[4];
    #pragma unroll
    for (int i = 0; i < 4; ++i)
      lv[i] = 1.0f / __shfl(v, quad * 4 + i);
    #pragma unroll
    for (int nc = 0; nc < 8; ++nc)
      #pragma unroll
      for (int i = 0; i < 4; ++i) {
        int qg = row0w + mt * 16 + quad * 4 + i;
        Ctx[(size_t)(b * S + qg) * 2048 + h * 128 + nc * 16 + col] =
            f2bf(o[mt][nc][i] * lv[i]);
      }
  }
}

extern "C" void kernel_launch(void* const* d_in, const int* in_sizes, int n_in,
                              void* d_out, int out_size, void* d_ws, size_t ws_size,
                              hipStream_t stream) {
  const int B = 2, S = 2048, D = 2048;
  const int M = B * S;            // 4096
  const int NQKV = 3072;          // q 0..2047 | k 2048..2559 | v 2560..3071

  const float* x  = (const float*)d_in[0];
  const float* wq = (const float*)d_in[1];
  const float* wk = (const float*)d_in[2];
  const float* wv = (const float*)d_in[3];
  const float* wo = (const float*)d_in[4];

  char* ws = (char*)d_ws;
  u16* xb    = (u16*)ws; ws += (size_t)M * D * 2;
  u16* wqkvb = (u16*)ws; ws += (size_t)NQKV * D * 2;
  u16* wob   = (u16*)ws; ws += (size_t)D * D * 2;
  u16* qkvb  = (u16*)ws; ws += (size_t)M * NQKV * 2;
  u16* vtg   = (u16*)ws; ws += (size_t)B * 4 * 128 * S * 2;
  u16* ctx   = (u16*)ws; ws += (size_t)M * D * 2;

  cast_all<<<18432, 256, 0, stream>>>(x, wq, wk, wv, wo, xb, wqkvb, wob);

  // QKV GEMM with fused RoPE epilogue (q also scaled by log2e/sqrt(128))
  gemm_bt<<<dim3(NQKV / 128, M / 128), 256, 0, stream>>>(xb, wqkvb, qkvb, M, NQKV, D, 0, 1);

  vtrans_kernel<<<dim3(S / 64, 2, B * 4), 256, 0, stream>>>(qkvb, vtg, S);

  attn_kernel<<<512, 256, 0, stream>>>(qkvb, vtg, ctx, B, S);

  gemm_bt<<<dim3(D / 128, M / 128), 256, 0, stream>>>(ctx, wob, d_out, M, D, D, 1, 0);
}

// Round 5
// 293.341 us; speedup vs baseline: 1.1844x; 1.0123x over previous
//
#include <hip/hip_runtime.h>
#include <stdint.h>

typedef unsigned short u16;
typedef __attribute__((ext_vector_type(8))) __bf16 bf16x8;
typedef __attribute__((ext_vector_type(4))) float f32x4;

__device__ __forceinline__ u16 f2bf(float f) {
  union { float f; uint32_t u; } v; v.f = f;
  uint32_t u = v.u;
  uint32_t r = (u + 0x7fffu + ((u >> 16) & 1u)) >> 16;  // RNE
  return (u16)r;
}
__device__ __forceinline__ float bf2f(u16 h) {
  union { uint32_t u; float f; } v; v.u = ((uint32_t)h) << 16;
  return v.f;
}

// async 16B/lane global->LDS. LDS dest = wave-uniform base + lane*16 (m104).
__device__ __forceinline__ void gld16(const void* g, void* l) {
  __builtin_amdgcn_global_load_lds(
      (__attribute__((address_space(1))) void*)(uintptr_t)g,
      (__attribute__((address_space(3))) void*)l,
      16, 0, 0);
}

// ---------------- fused fp32 -> bf16 cast of all 5 inputs (grid-stride) ----------------
__global__ __launch_bounds__(256) void cast_all(const float* __restrict__ x,
                                                const float* __restrict__ wq,
                                                const float* __restrict__ wk,
                                                const float* __restrict__ wv,
                                                const float* __restrict__ wo,
                                                u16* __restrict__ xb,
                                                u16* __restrict__ wqkv,
                                                u16* __restrict__ wob) {
  // total float4 elements: x 2097152 | wq 1048576 | wk 262144 | wv 262144 | wo 1048576
  for (int i = blockIdx.x * 256 + threadIdx.x; i < 4718592; i += 2048 * 256) {
    const float* src; u16* dst; int loc, base;
    if (i < 2097152)      { src = x;  dst = xb;   loc = i;           base = 0; }
    else if (i < 3145728) { src = wq; dst = wqkv; loc = i - 2097152; base = 0; }
    else if (i < 3407872) { src = wk; dst = wqkv; loc = i - 3145728; base = 1048576; }
    else if (i < 3670016) { src = wv; dst = wqkv; loc = i - 3407872; base = 1310720; }
    else                  { src = wo; dst = wob;  loc = i - 3670016; base = 0; }
    float4 f = ((const float4*)src)[loc];
    ushort4 o;
    o.x = f2bf(f.x); o.y = f2bf(f.y); o.z = f2bf(f.z); o.w = f2bf(f.w);
    ((ushort4*)dst)[base + loc] = o;
  }
}

// ---------------- bf16 GEMM, C = A * B^T  (BK=64, m97-style staging) ----------------
// do_rope (QKV GEMM): cols<2560 get fused RoPE (q cols also scaled by
// log2e/sqrt(128)) and go to C; v-cols (>=2560) are written TRANSPOSED to
// Vtg[(b*4+kvh)*128+d][s] (replaces the standalone vtrans kernel) and are NOT
// written to C. XCD-contiguous block swizzle (T1) for L2 locality.
__global__ __launch_bounds__(256) void gemm_bt(const u16* __restrict__ A,
                                               const u16* __restrict__ B,
                                               void* __restrict__ C,
                                               u16* __restrict__ Vtg,
                                               int M, int N, int K, int out_f32,
                                               int do_rope)
{
  __shared__ u16 As[128 * 64];
  __shared__ u16 Bs[128 * 64];
  const int tid  = threadIdx.x;
  const int wave = tid >> 6, lane = tid & 63;
  const int col  = lane & 15, quad = lane >> 4;

  // T1: XCD-contiguous work remap (grids here are %8==0; guarded fallback).
  const int nwg = gridDim.x * gridDim.y;
  int flat = blockIdx.y * gridDim.x + blockIdx.x;
  int swz  = (nwg & 7) ? flat : ((flat & 7) * (nwg >> 3) + (flat >> 3));
  const int bm = swz / gridDim.x, bn = swz % gridDim.x;

  const int wm = (wave >> 1) * 64, wn = (wave & 1) * 64;
  const size_t arow0 = (size_t)bm * 128, brow0 = (size_t)bn * 128;

  const int sr = lane >> 3, pc = lane & 7;

  const f32x4 fz = {0.f, 0.f, 0.f, 0.f};
  f32x4 acc[4][4];
  for (int i = 0; i < 4; ++i)
    for (int j = 0; j < 4; ++j) acc[i][j] = fz;

  for (int k0 = 0; k0 < K; k0 += 64) {
    __syncthreads();
    #pragma unroll
    for (int i = 0; i < 4; ++i) {
      int rA = wave * 32 + i * 8 + sr;
      int lc = pc ^ (rA & 7);
      gld16(A + (arow0 + rA) * K + k0 + lc * 8, As + (wave * 32 + i * 8) * 64);
      gld16(B + (brow0 + rA) * K + k0 + lc * 8, Bs + (wave * 32 + i * 8) * 64);
    }
    __syncthreads();
    #pragma unroll
    for (int kk = 0; kk < 2; ++kk) {
      const int swzk = (((kk * 4 + quad) ^ (col & 7)) * 8);
      bf16x8 af[4];
      #pragma unroll
      for (int mt = 0; mt < 4; ++mt)
        af[mt] = *(const bf16x8*)&As[(wm + mt * 16 + col) * 64 + swzk];
      #pragma unroll
      for (int nt = 0; nt < 4; ++nt) {
        bf16x8 bf = *(const bf16x8*)&Bs[(wn + nt * 16 + col) * 64 + swzk];
        #pragma unroll
        for (int mt = 0; mt < 4; ++mt)
          acc[mt][nt] = __builtin_amdgcn_mfma_f32_16x16x32_bf16(af[mt], bf, acc[mt][nt], 0, 0, 0);
      }
    }
  }

  // epilogue (+ optional fused RoPE / transposed-V write)
  const float qscale = 0.12751744515623627f;  // log2(e)/sqrt(128)
  #pragma unroll
  for (int mt = 0; mt < 4; ++mt)
    #pragma unroll
    for (int nt = 0; nt < 4; ++nt) {
      const size_t gcol = brow0 + wn + nt * 16 + col;
      // wave-uniform: 16-col group entirely inside one region
      const bool v_here    = do_rope && (gcol >= 2560);
      const bool rope_here = do_rope && (gcol < 2560);
      const int  d    = (int)(gcol & 127);
      const float osc = (gcol < 2048) ? qscale : 1.0f;
      const float inv = exp2f(-(float)(d >> 1) * 0.20762050593046f);  // 10000^(-2i/128)
      const bool odd  = (d & 1) != 0;
      if (v_here) {
        // transposed V write: 4 consecutive token positions s -> one ushort4
        const int vc  = (int)gcol - 2560;
        const int kvh = vc >> 7;
        const size_t grow0 = arow0 + wm + mt * 16 + quad * 4;   // b*2048 + s0
        const int bb = (int)(grow0 >> 11);
        const int s0 = (int)(grow0 & 2047);
        ushort4 o4;
        o4.x = f2bf(acc[mt][nt][0]);
        o4.y = f2bf(acc[mt][nt][1]);
        o4.z = f2bf(acc[mt][nt][2]);
        o4.w = f2bf(acc[mt][nt][3]);
        *(ushort4*)&Vtg[((size_t)((bb * 4 + kvh) * 128 + d)) * 2048 + s0] = o4;
        continue;
      }
      #pragma unroll
      for (int i = 0; i < 4; ++i) {
        size_t grow = arow0 + wm + mt * 16 + quad * 4 + i;
        float v = acc[mt][nt][i];
        if (rope_here) {
          float p = __shfl_xor(v, 1);            // partner column d^1
          float ang = (float)(int)(grow & 2047) * inv;  // s = token pos (S=2048)
          float sn, cs;
          __sincosf(ang, &sn, &cs);
          v = odd ? (p * sn + v * cs) * osc : (v * cs - p * sn) * osc;
        }
        if (out_f32) ((float*)C)[grow * N + gcol] = v;
        else         ((u16*)C)[grow * N + gcol]   = f2bf(v);
      }
    }
}

// ---------------- causal flash attention, GQA 4:1, no-max softmax ----------------
// (round-0 structure, verbatim: 2 barriers/tile, single-buffered K/V staging)
__global__ __launch_bounds__(256, 2) void attn_kernel(const u16* __restrict__ QKV,
                                                      const u16* __restrict__ Vtg,
                                                      u16* __restrict__ Ctx,
                                                      int B, int S)
{
  const int x = blockIdx.x;                 // 512 blocks
  const int t = x >> 5, bh = x & 31;
  const int qt = (x < 256) ? (15 - t) : (t - 8);   // heavy first; pairs (c,c+256) sum 15
  const int h = bh & 15, b = bh >> 4;
  const int tid  = threadIdx.x;
  const int wave = tid >> 6, lane = tid & 63;
  const int col  = lane & 15, quad = lane >> 4;
  const int q0   = qt * 128;
  const int kvh  = h >> 2;
  const int row0w = q0 + wave * 32;

  __shared__ u16 Ks[64 * 128];    // [key][d], 16B chunks phys = c ^ (key&15)
  __shared__ u16 Vt[128 * 64];    // [d][key], 16B chunks phys = c ^ (d&7)
  __shared__ u16 Ps[4][32 * 72];  // per-wave P: [qrow][key], stride 72

  // Q B-operand frags (scale log2e/sqrt(128) pre-folded in rope)
  bf16x8 aq[2][4];
  #pragma unroll
  for (int mt = 0; mt < 2; ++mt)
    #pragma unroll
    for (int ks = 0; ks < 4; ++ks)
      aq[mt][ks] = *(const bf16x8*)(QKV + (size_t)(b * S + row0w + mt * 16 + col) * 3072
                                        + h * 128 + ks * 32 + quad * 8);

  const u16* KVb = QKV + (size_t)b * S * 3072 + 2048 + kvh * 128;
  const u16* Vtb = Vtg + ((size_t)(b * 4 + kvh) * 128) * S;
  u16* Pw = Ps[wave];

  const f32x4 fz = {0.f, 0.f, 0.f, 0.f};
  f32x4 o[2][8];
  #pragma unroll
  for (int mt = 0; mt < 2; ++mt)
    #pragma unroll
    for (int nc = 0; nc < 8; ++nc) o[mt][nc] = fz;
  float rs[2] = {0.f, 0.f};   // per-lane: qrow = row0w + mt*16 + col

  const int kt_max = 2 * qt + 1;

  for (int kt = 0; kt <= kt_max; ++kt) {
    __syncthreads();   // prior tile reads done
    // stage K: 64 rows x 16 chunks; per wave 4 issues x 4 rows
    #pragma unroll
    for (int i = 0; i < 4; ++i) {
      int r = wave * 16 + i * 4 + (lane >> 4);
      int lc = (lane & 15) ^ (r & 15);
      gld16(KVb + (size_t)(kt * 64 + r) * 3072 + lc * 8, Ks + (wave * 16 + i * 4) * 128);
    }
    // stage V^T: 128 rows x 8 chunks; per wave 4 issues x 8 rows
    #pragma unroll
    for (int i = 0; i < 4; ++i) {
      int r = wave * 32 + i * 8 + (lane >> 3);
      int lc = (lane & 7) ^ (r & 7);
      gld16(Vtb + (size_t)r * S + kt * 64 + lc * 8, Vt + (wave * 32 + i * 8) * 64);
    }
    __syncthreads();   // drain -> staged data visible

    if (kt * 64 > row0w + 31) continue;   // wave fully masked (uniform; barriers above)
    const bool need_mask = (kt * 64 + 63 > row0w);

    // S^T = K Q^T per 16-key group; write P[qrow][key] as b64
    #pragma unroll
    for (int nt = 0; nt < 4; ++nt) {
      bf16x8 kA[4];
      #pragma unroll
      for (int ks = 0; ks < 4; ++ks)
        kA[ks] = *(const bf16x8*)&Ks[(nt * 16 + col) * 128 + (((ks * 4 + quad) ^ col) * 8)];
      #pragma unroll
      for (int mt = 0; mt < 2; ++mt) {
        f32x4 st = fz;
        #pragma unroll
        for (int ks = 0; ks < 4; ++ks)
          st = __builtin_amdgcn_mfma_f32_16x16x32_bf16(kA[ks], aq[mt][ks], st, 0, 0, 0);
        // lane: key = kt*64 + nt*16 + quad*4 + i, qrow = row0w + mt*16 + col
        float pv[4];
        const int kbase = kt * 64 + nt * 16 + quad * 4;
        const int qrow  = row0w + mt * 16 + col;
        #pragma unroll
        for (int i = 0; i < 4; ++i) {
          float s = st[i];
          if (need_mask && (kbase + i > qrow)) s = -__builtin_inff();
          pv[i] = exp2f(s);
        }
        rs[mt] += (pv[0] + pv[1]) + (pv[2] + pv[3]);
        uint32_t d0 = (__float_as_uint(pv[0]) >> 16) | (__float_as_uint(pv[1]) & 0xffff0000u);
        uint32_t d1 = (__float_as_uint(pv[2]) >> 16) | (__float_as_uint(pv[3]) & 0xffff0000u);
        uint2 dd; dd.x = d0; dd.y = d1;
        *(uint2*)&Pw[(mt * 16 + col) * 72 + nt * 16 + quad * 4] = dd;
      }
    }
    __asm__ volatile("" ::: "memory");

    // PV: P A-frags (b128), V^T B-frags read once, reused across mt
    bf16x8 ap[2][2];
    #pragma unroll
    for (int mt = 0; mt < 2; ++mt)
      #pragma unroll
      for (int ks = 0; ks < 2; ++ks)
        ap[mt][ks] = *(const bf16x8*)&Pw[(mt * 16 + col) * 72 + ks * 32 + quad * 8];
    #pragma unroll
    for (int nc = 0; nc < 8; ++nc) {
      #pragma unroll
      for (int ks = 0; ks < 2; ++ks) {
        bf16x8 bv = *(const bf16x8*)&Vt[(nc * 16 + col) * 64 + (((ks * 4 + quad) ^ (col & 7)) * 8)];
        #pragma unroll
        for (int mt = 0; mt < 2; ++mt)
          o[mt][nc] = __builtin_amdgcn_mfma_f32_16x16x32_bf16(ap[mt][ks], bv, o[mt][nc], 0, 0, 0);
      }
    }
  }

  // epilogue: reduce rs over the 4 quad-copies, normalize, store
  #pragma unroll
  for (int mt = 0; mt < 2; ++mt) {
    float v = rs[mt];
    v += __shfl_xor(v, 16);
    v += __shfl_xor(v, 32);
    float lv[4];
    #pragma unroll
    for (int i = 0; i < 4; ++i)
      lv[i] = 1.0f / __shfl(v, quad * 4 + i);
    #pragma unroll
    for (int nc = 0; nc < 8; ++nc)
      #pragma unroll
      for (int i = 0; i < 4; ++i) {
        int qg = row0w + mt * 16 + quad * 4 + i;
        Ctx[(size_t)(b * S + qg) * 2048 + h * 128 + nc * 16 + col] =
            f2bf(o[mt][nc][i] * lv[i]);
      }
  }
}

extern "C" void kernel_launch(void* const* d_in, const int* in_sizes, int n_in,
                              void* d_out, int out_size, void* d_ws, size_t ws_size,
                              hipStream_t stream) {
  const int B = 2, S = 2048, D = 2048;
  const int M = B * S;            // 4096
  const int NQKV = 3072;          // q 0..2047 | k 2048..2559 | v 2560..3071 (v -> Vtg only)

  const float* x  = (const float*)d_in[0];
  const float* wq = (const float*)d_in[1];
  const float* wk = (const float*)d_in[2];
  const float* wv = (const float*)d_in[3];
  const float* wo = (const float*)d_in[4];

  char* ws = (char*)d_ws;
  u16* xb    = (u16*)ws; ws += (size_t)M * D * 2;
  u16* wqkvb = (u16*)ws; ws += (size_t)NQKV * D * 2;
  u16* wob   = (u16*)ws; ws += (size_t)D * D * 2;
  u16* qkvb  = (u16*)ws; ws += (size_t)M * NQKV * 2;
  u16* vtg   = (u16*)ws; ws += (size_t)B * 4 * 128 * S * 2;
  u16* ctx   = (u16*)ws; ws += (size_t)M * D * 2;

  cast_all<<<2048, 256, 0, stream>>>(x, wq, wk, wv, wo, xb, wqkvb, wob);

  // QKV GEMM with fused RoPE epilogue + transposed-V write (vtrans eliminated)
  gemm_bt<<<dim3(NQKV / 128, M / 128), 256, 0, stream>>>(xb, wqkvb, qkvb, vtg, M, NQKV, D, 0, 1);

  attn_kernel<<<512, 256, 0, stream>>>(qkvb, vtg, ctx, B, S);

  gemm_bt<<<dim3(D / 128, M / 128), 256, 0, stream>>>(ctx, wob, d_out, vtg, M, D, D, 1, 0);
}